// Round 23
// baseline (137.898 us; speedup 1.0000x reference)
//
#include <hip/hip_runtime.h>
#include <math.h>

constexpr int NQ      = 14;
constexpr int NSTATE  = 1 << 14;    // 16384
constexpr int NPARAMS = 140;
constexpr int BATCH   = 128;
constexpr int THREADS = 1024;
constexpr int REGS    = 16;         // amps per thread: global index i = (tid<<4)|r

struct cplx { float re, im; };
__device__ __forceinline__ cplx cmul(cplx a, cplx b) {
    return { a.re*b.re - a.im*b.im, a.re*b.im + a.im*b.re };
}
__device__ __forceinline__ float2 axpb(cplx A, float2 own, cplx B, float2 par) {
    return make_float2(A.re*own.x - A.im*own.y + B.re*par.x - B.im*par.y,
                       A.re*own.y + A.im*own.x + B.re*par.y + B.im*par.x);
}
__device__ __forceinline__ unsigned int f2bf(float f) {
    union { float f; unsigned int u; } v; v.f = f;
    return (v.u + 0x7FFFu + ((v.u >> 16) & 1u)) >> 16;
}
// insert a set bit at position PCL into 3-bit index j
__device__ __forceinline__ int ins1(int j, int pcl) {
    int lo = j & ((1 << pcl) - 1);
    return ((j ^ lo) << 1) | (1 << pcl) | lo;
}

// ---------- 1q gate, register bit P (0..3) ----------
template<int P>
__device__ __forceinline__ void u1_local(float2 (&a)[REGS],
                                         cplx u00, cplx u01, cplx u10, cplx u11) {
    #pragma unroll
    for (int r = 0; r < REGS; ++r) {
        if (r & (1 << P)) continue;
        const int r1 = r | (1 << P);
        float2 n0 = axpb(u00, a[r],  u01, a[r1]);
        float2 n1 = axpb(u11, a[r1], u10, a[r]);
        a[r] = n0; a[r1] = n1;
    }
}

// ---------- 1q gate, lane bit (MASK = 1..32) ----------
template<int MASK>
__device__ __forceinline__ void u1_lane(float2 (&a)[REGS], int tid,
                                        cplx u00, cplx u01, cplx u10, cplx u11) {
    const bool hi = (tid & MASK) != 0;
    const cplx A = hi ? u11 : u00;
    const cplx B = hi ? u10 : u01;
    #pragma unroll
    for (int r = 0; r < REGS; ++r) {
        float px = __shfl_xor(a[r].x, MASK, 64);
        float py = __shfl_xor(a[r].y, MASK, 64);
        a[r] = axpb(A, a[r], B, make_float2(px, py));
    }
}

// ---------- 1q gate, wave bit (tmask = tid-space bit 64..512) ----------
__device__ __forceinline__ void u1_wave(float2 (&a)[REGS], int tid, int tmask,
                                        cplx u00, cplx u01, cplx u10, cplx u11,
                                        float4* xch) {
    const bool hi = (tid & tmask) != 0;
    const cplx A = hi ? u11 : u00;
    const cplx B = hi ? u10 : u01;
    __syncthreads();                       // previous xch readers done
    #pragma unroll
    for (int j = 0; j < 8; ++j)            // column-major: conflict-free b128
        xch[j*1024 + tid] = make_float4(a[2*j].x, a[2*j].y, a[2*j+1].x, a[2*j+1].y);
    __syncthreads();
    const int pr = tid ^ tmask;
    #pragma unroll
    for (int j = 0; j < 8; ++j) {
        float4 p = xch[j*1024 + pr];
        a[2*j]   = axpb(A, a[2*j],   B, make_float2(p.x, p.y));
        a[2*j+1] = axpb(A, a[2*j+1], B, make_float2(p.z, p.w));
    }
}

// ---------- CRX, target reg bit PT (0..3) ----------
template<int PT>
__device__ __forceinline__ void crx_local(float2 (&a)[REGS], int tid, int pc,
                                          float cr, float sr) {
    #pragma unroll
    for (int r = 0; r < REGS; ++r) {
        if (r & (1 << PT)) continue;
        const int r1 = r | (1 << PT);
        const int i0 = (tid << 4) | r;
        const bool act = ((i0 >> pc) & 1) != 0;
        if (act) {
            float2 a0 = a[r], a1 = a[r1];
            a[r]  = make_float2(cr*a0.x + sr*a1.y, cr*a0.y - sr*a1.x);
            a[r1] = make_float2(cr*a1.x + sr*a0.y, cr*a1.y - sr*a0.x);
        }
    }
}

// ---------- CRX, target lane bit ----------
template<int MASK>
__device__ __forceinline__ void crx_lane(float2 (&a)[REGS], int tid, int pc,
                                         float cr, float sr) {
    if (pc >= 4) {
        const bool act = ((tid >> (pc - 4)) & 1) != 0;
        #pragma unroll
        for (int r = 0; r < REGS; ++r) {
            if (act) {
                float px = __shfl_xor(a[r].x, MASK, 64);
                float py = __shfl_xor(a[r].y, MASK, 64);
                a[r] = make_float2(cr*a[r].x + sr*py, cr*a[r].y - sr*px);
            }
        }
    } else {
        #pragma unroll
        for (int r = 0; r < REGS; ++r) {
            if (((r >> pc) & 1) == 0) continue;      // inactive reg: skip shuffle
            float px = __shfl_xor(a[r].x, MASK, 64);
            float py = __shfl_xor(a[r].y, MASK, 64);
            a[r] = make_float2(cr*a[r].x + sr*py, cr*a[r].y - sr*px);
        }
    }
}

// ---------- CRX, target wave bit, control bit >= 4 (thread-level act) ----------
__device__ __forceinline__ void crx_wave_hi(float2 (&a)[REGS], int tid, int tmask,
                                            int pcb /*1<<(pc-4)*/,
                                            float cr, float sr, float4* xch) {
    const bool act = (tid & pcb) != 0;
    __syncthreads();
    if (act) {
        #pragma unroll
        for (int j = 0; j < 8; ++j)
            xch[j*1024 + tid] = make_float4(a[2*j].x, a[2*j].y, a[2*j+1].x, a[2*j+1].y);
    }
    __syncthreads();
    if (act) {
        const int pr = tid ^ tmask;
        #pragma unroll
        for (int j = 0; j < 8; ++j) {
            float4 p = xch[j*1024 + pr];
            a[2*j]   = make_float2(cr*a[2*j].x   + sr*p.y, cr*a[2*j].y   - sr*p.x);
            a[2*j+1] = make_float2(cr*a[2*j+1].x + sr*p.w, cr*a[2*j+1].y - sr*p.z);
        }
    }
}

// ---------- CRX, target wave bit, control reg bit PCL (0..3): 8 active regs ----------
template<int PCL>
__device__ __forceinline__ void crx_wave_lo(float2 (&a)[REGS], int tid, int tmask,
                                            float cr, float sr, float4* xch) {
    __syncthreads();
    #pragma unroll
    for (int j2 = 0; j2 < 4; ++j2) {
        const int ra = ins1(2*j2, PCL), rb = ins1(2*j2+1, PCL);
        xch[j2*1024 + tid] = make_float4(a[ra].x, a[ra].y, a[rb].x, a[rb].y);
    }
    __syncthreads();
    const int pr = tid ^ tmask;
    #pragma unroll
    for (int j2 = 0; j2 < 4; ++j2) {
        const int ra = ins1(2*j2, PCL), rb = ins1(2*j2+1, PCL);
        float4 p = xch[j2*1024 + pr];
        a[ra] = make_float2(cr*a[ra].x + sr*p.y, cr*a[ra].y - sr*p.x);
        a[rb] = make_float2(cr*a[rb].x + sr*p.w, cr*a[rb].y - sr*p.z);
    }
}

// ---------- drivers ----------
__device__ __forceinline__ void fused1q(float2 (&a)[REGS], int tid, int q, int idx,
                                        const float2* gcs, float4* xch) {
    const float2 x = gcs[idx], y = gcs[idx + 1], z = gcs[idx + 2];
    const float cx = x.x, sx = x.y, cy = y.x, sy = y.y, cz = z.x, sz = z.y;
    cplx m00{ cy*cx,  sy*sx }, m01{ -sy*cx, -cy*sx };
    cplx m10{ sy*cx, -cy*sx }, m11{  cy*cx, -sy*sx };
    cplx z0{ cz, -sz }, z1{ cz, sz };
    cplx u00 = cmul(z0, m00), u01 = cmul(z0, m01);
    cplx u10 = cmul(z1, m10), u11 = cmul(z1, m11);
    const int p = NQ - 1 - q;
    switch (p) {
        case 0:  u1_local<0>(a, u00, u01, u10, u11); break;
        case 1:  u1_local<1>(a, u00, u01, u10, u11); break;
        case 2:  u1_local<2>(a, u00, u01, u10, u11); break;
        case 3:  u1_local<3>(a, u00, u01, u10, u11); break;
        case 4:  u1_lane<1> (a, tid, u00, u01, u10, u11); break;
        case 5:  u1_lane<2> (a, tid, u00, u01, u10, u11); break;
        case 6:  u1_lane<4> (a, tid, u00, u01, u10, u11); break;
        case 7:  u1_lane<8> (a, tid, u00, u01, u10, u11); break;
        case 8:  u1_lane<16>(a, tid, u00, u01, u10, u11); break;
        case 9:  u1_lane<32>(a, tid, u00, u01, u10, u11); break;
        default: u1_wave(a, tid, 1 << (p - 4), u00, u01, u10, u11, xch); break;
    }
}

__device__ __forceinline__ void crx(float2 (&a)[REGS], int tid, int c, int t, int idx,
                                    const float2* gcs, float4* xch) {
    const float2 g = gcs[idx];
    const float cr = g.x, sr = g.y;
    const int pc = NQ - 1 - c, pt = NQ - 1 - t;
    switch (pt) {
        case 0:  crx_local<0>(a, tid, pc, cr, sr); break;
        case 1:  crx_local<1>(a, tid, pc, cr, sr); break;
        case 2:  crx_local<2>(a, tid, pc, cr, sr); break;
        case 3:  crx_local<3>(a, tid, pc, cr, sr); break;
        case 4:  crx_lane<1> (a, tid, pc, cr, sr); break;
        case 5:  crx_lane<2> (a, tid, pc, cr, sr); break;
        case 6:  crx_lane<4> (a, tid, pc, cr, sr); break;
        case 7:  crx_lane<8> (a, tid, pc, cr, sr); break;
        case 8:  crx_lane<16>(a, tid, pc, cr, sr); break;
        case 9:  crx_lane<32>(a, tid, pc, cr, sr); break;
        default: {
            const int tmask = 1 << (pt - 4);
            if (pc < 4) {
                switch (pc) {
                    case 0: crx_wave_lo<0>(a, tid, tmask, cr, sr, xch); break;
                    case 1: crx_wave_lo<1>(a, tid, tmask, cr, sr, xch); break;
                    case 2: crx_wave_lo<2>(a, tid, tmask, cr, sr, xch); break;
                    case 3: crx_wave_lo<3>(a, tid, tmask, cr, sr, xch); break;
                }
            } else {
                crx_wave_hi(a, tid, tmask, 1 << (pc - 4), cr, sr, xch);
            }
            break;
        }
    }
}

__global__ __launch_bounds__(THREADS)
void qsim_kernel(const float* __restrict__ params,
                 unsigned int* __restrict__ out_u32) {
    __shared__ float4 xch[8192];       // 128 KiB exchange, column-major [8][1024]
    __shared__ float2 gcs[NPARAMS];    // (cos, sin) of half-angles

    const int b   = blockIdx.x;
    const int tid = threadIdx.x;

    if (tid < NPARAMS) {
        float s, c;
        sincosf(0.5f * params[b * NPARAMS + tid], &s, &c);
        gcs[tid] = make_float2(c, s);
    }

    float2 a[REGS];
    #pragma unroll
    for (int r = 0; r < REGS; ++r) a[r] = make_float2(0.f, 0.f);
    if (tid == 0) a[0] = make_float2(1.f, 0.f);
    __syncthreads();

    int idx = 0;
    for (int layer = 0; layer < 2; ++layer) {
        for (int q = 0; q < NQ; ++q)      { fused1q(a, tid, q, idx, gcs, xch); idx += 3; }
        for (int i = 0; i < NQ; ++i)      { crx(a, tid, i, (i + 1) % NQ,  idx, gcs, xch); idx += 1; }
        for (int i = NQ - 1; i >= 0; --i) { crx(a, tid, i, (i + 13) % NQ, idx, gcs, xch); idx += 1; }
    }

    // ---- epilogue: IMAG-FIRST interleaved bf16: low=Im, high=Re ----
    uint4* ob = (uint4*)(out_u32 + (size_t)b * NSTATE + tid * REGS);
    #pragma unroll
    for (int m = 0; m < 4; ++m) {
        uint4 w;
        w.x = f2bf(a[4*m    ].y) | (f2bf(a[4*m    ].x) << 16);
        w.y = f2bf(a[4*m + 1].y) | (f2bf(a[4*m + 1].x) << 16);
        w.z = f2bf(a[4*m + 2].y) | (f2bf(a[4*m + 2].x) << 16);
        w.w = f2bf(a[4*m + 3].y) | (f2bf(a[4*m + 3].x) << 16);
        ob[m] = w;
    }
}

extern "C" void kernel_launch(void* const* d_in, const int* in_sizes, int n_in,
                              void* d_out, int out_size, void* d_ws, size_t ws_size,
                              hipStream_t stream) {
    const float* params = (const float*)d_in[0];
    unsigned int* out = (unsigned int*)d_out;
    qsim_kernel<<<BATCH, THREADS, 0, stream>>>(params, out);
}

// Round 24
// 110.424 us; speedup vs baseline: 1.2488x; 1.2488x over previous
//
#include <hip/hip_runtime.h>
#include <math.h>

constexpr int NQ      = 14;
constexpr int NSTATE  = 1 << 14;    // 16384
constexpr int NPARAMS = 140;
constexpr int BATCH   = 128;
constexpr int THREADS = 1024;
constexpr int REGS    = 16;         // amps per thread: global index i = (tid<<4)|r

struct cplx { float re, im; };
__device__ __forceinline__ cplx cmul(cplx a, cplx b) {
    return { a.re*b.re - a.im*b.im, a.re*b.im + a.im*b.re };
}
__device__ __forceinline__ float2 axpb(cplx A, float2 own, cplx B, float2 par) {
    return make_float2(A.re*own.x - A.im*own.y + B.re*par.x - B.im*par.y,
                       A.re*own.y + A.im*own.x + B.re*par.y + B.im*par.x);
}
__device__ __forceinline__ unsigned int f2bf(float f) {
    union { float f; unsigned int u; } v; v.f = f;
    return (v.u + 0x7FFFu + ((v.u >> 16) & 1u)) >> 16;
}
// insert a set bit at position PCL into 3-bit index j (compile-time use only)
__device__ __forceinline__ constexpr int ins1(int j, int pcl) {
    int lo = j & ((1 << pcl) - 1);
    return ((j ^ lo) << 1) | (1 << pcl) | lo;
}

// ---------- 1q gate, register bit P (0..3) ----------
template<int P>
__device__ __forceinline__ void u1_local(float2 (&a)[REGS],
                                         cplx u00, cplx u01, cplx u10, cplx u11) {
    #pragma unroll
    for (int r = 0; r < REGS; ++r) {
        if (r & (1 << P)) continue;
        const int r1 = r | (1 << P);
        float2 n0 = axpb(u00, a[r],  u01, a[r1]);
        float2 n1 = axpb(u11, a[r1], u10, a[r]);
        a[r] = n0; a[r1] = n1;
    }
}

// ---------- 1q gate, lane bit (MASK = 1..32) ----------
template<int MASK>
__device__ __forceinline__ void u1_lane(float2 (&a)[REGS], int tid,
                                        cplx u00, cplx u01, cplx u10, cplx u11) {
    const bool hi = (tid & MASK) != 0;
    const cplx A = hi ? u11 : u00;
    const cplx B = hi ? u10 : u01;
    #pragma unroll
    for (int r = 0; r < REGS; ++r) {
        float px = __shfl_xor(a[r].x, MASK, 64);
        float py = __shfl_xor(a[r].y, MASK, 64);
        a[r] = axpb(A, a[r], B, make_float2(px, py));
    }
}

// ---------- 1q gate, wave bit TMASK (64..512 in tid space) ----------
template<int TMASK>
__device__ __forceinline__ void u1_wave(float2 (&a)[REGS], int tid,
                                        cplx u00, cplx u01, cplx u10, cplx u11,
                                        float4* xch) {
    const bool hi = (tid & TMASK) != 0;
    const cplx A = hi ? u11 : u00;
    const cplx B = hi ? u10 : u01;
    __syncthreads();                       // previous xch readers done
    #pragma unroll
    for (int j = 0; j < 8; ++j)            // column-major: conflict-free b128
        xch[j*1024 + tid] = make_float4(a[2*j].x, a[2*j].y, a[2*j+1].x, a[2*j+1].y);
    __syncthreads();
    const int pr = tid ^ TMASK;
    #pragma unroll
    for (int j = 0; j < 8; ++j) {
        float4 p = xch[j*1024 + pr];
        a[2*j]   = axpb(A, a[2*j],   B, make_float2(p.x, p.y));
        a[2*j+1] = axpb(A, a[2*j+1], B, make_float2(p.z, p.w));
    }
}

// ---------- CRX, target reg bit PT (0..3), control bit PC (compile-time) ----------
template<int PT, int PC>
__device__ __forceinline__ void crx_local(float2 (&a)[REGS], int tid,
                                          float cr, float sr) {
    #pragma unroll
    for (int r = 0; r < REGS; ++r) {
        if (r & (1 << PT)) continue;
        const int r1 = r | (1 << PT);
        const bool act = ((((tid << 4) | r) >> PC) & 1) != 0;
        if (act) {
            float2 a0 = a[r], a1 = a[r1];
            a[r]  = make_float2(cr*a0.x + sr*a1.y, cr*a0.y - sr*a1.x);
            a[r1] = make_float2(cr*a1.x + sr*a0.y, cr*a1.y - sr*a0.x);
        }
    }
}

// ---------- CRX, target lane bit MASK, control bit PC ----------
template<int MASK, int PC>
__device__ __forceinline__ void crx_lane(float2 (&a)[REGS], int tid,
                                         float cr, float sr) {
    if (PC >= 4) {
        const bool act = ((tid >> (PC - 4)) & 1) != 0;
        #pragma unroll
        for (int r = 0; r < REGS; ++r) {
            float px = __shfl_xor(a[r].x, MASK, 64);
            float py = __shfl_xor(a[r].y, MASK, 64);
            if (act) a[r] = make_float2(cr*a[r].x + sr*py, cr*a[r].y - sr*px);
        }
    } else {
        #pragma unroll
        for (int r = 0; r < REGS; ++r) {
            if (((r >> PC) & 1) == 0) continue;      // inactive reg: skip shuffle
            float px = __shfl_xor(a[r].x, MASK, 64);
            float py = __shfl_xor(a[r].y, MASK, 64);
            a[r] = make_float2(cr*a[r].x + sr*py, cr*a[r].y - sr*px);
        }
    }
}

// ---------- CRX, target wave bit TMASK, control bit PC >= 4 ----------
template<int TMASK, int PC>
__device__ __forceinline__ void crx_wave_hi(float2 (&a)[REGS], int tid,
                                            float cr, float sr, float4* xch) {
    const bool act = (tid & (1 << (PC - 4))) != 0;
    __syncthreads();
    if (act) {
        #pragma unroll
        for (int j = 0; j < 8; ++j)
            xch[j*1024 + tid] = make_float4(a[2*j].x, a[2*j].y, a[2*j+1].x, a[2*j+1].y);
    }
    __syncthreads();
    if (act) {
        const int pr = tid ^ TMASK;
        #pragma unroll
        for (int j = 0; j < 8; ++j) {
            float4 p = xch[j*1024 + pr];
            a[2*j]   = make_float2(cr*a[2*j].x   + sr*p.y, cr*a[2*j].y   - sr*p.x);
            a[2*j+1] = make_float2(cr*a[2*j+1].x + sr*p.w, cr*a[2*j+1].y - sr*p.z);
        }
    }
}

// ---------- CRX, target wave bit TMASK, control reg bit PCL (0..3) ----------
template<int TMASK, int PCL>
__device__ __forceinline__ void crx_wave_lo(float2 (&a)[REGS], int tid,
                                            float cr, float sr, float4* xch) {
    __syncthreads();
    #pragma unroll
    for (int j2 = 0; j2 < 4; ++j2) {
        constexpr int ra0[4] = { ins1(0,PCL), ins1(2,PCL), ins1(4,PCL), ins1(6,PCL) };
        constexpr int rb0[4] = { ins1(1,PCL), ins1(3,PCL), ins1(5,PCL), ins1(7,PCL) };
        xch[j2*1024 + tid] = make_float4(a[ra0[j2]].x, a[ra0[j2]].y,
                                         a[rb0[j2]].x, a[rb0[j2]].y);
    }
    __syncthreads();
    const int pr = tid ^ TMASK;
    #pragma unroll
    for (int j2 = 0; j2 < 4; ++j2) {
        constexpr int ra0[4] = { ins1(0,PCL), ins1(2,PCL), ins1(4,PCL), ins1(6,PCL) };
        constexpr int rb0[4] = { ins1(1,PCL), ins1(3,PCL), ins1(5,PCL), ins1(7,PCL) };
        float4 p = xch[j2*1024 + pr];
        const int ra = ra0[j2], rb = rb0[j2];
        a[ra] = make_float2(cr*a[ra].x + sr*p.y, cr*a[ra].y - sr*p.x);
        a[rb] = make_float2(cr*a[rb].x + sr*p.w, cr*a[rb].y - sr*p.z);
    }
}

// ---------- compile-time dispatchers ----------
template<int P>
__device__ __forceinline__ void fused1q_t(float2 (&a)[REGS], int tid, int idx,
                                          const float2* gcs, float4* xch) {
    const float2 x = gcs[idx], y = gcs[idx + 1], z = gcs[idx + 2];
    const float cx = x.x, sx = x.y, cy = y.x, sy = y.y, cz = z.x, sz = z.y;
    cplx m00{ cy*cx,  sy*sx }, m01{ -sy*cx, -cy*sx };
    cplx m10{ sy*cx, -cy*sx }, m11{  cy*cx, -sy*sx };
    cplx z0{ cz, -sz }, z1{ cz, sz };
    cplx u00 = cmul(z0, m00), u01 = cmul(z0, m01);
    cplx u10 = cmul(z1, m10), u11 = cmul(z1, m11);
    if constexpr (P < 4)       u1_local<(P < 4 ? P : 0)>(a, u00, u01, u10, u11);
    else if constexpr (P < 10) u1_lane<(P >= 4 && P < 10 ? (1 << (P - 4)) : 1)>(a, tid, u00, u01, u10, u11);
    else                       u1_wave<(P >= 10 ? (1 << (P - 4)) : 64)>(a, tid, u00, u01, u10, u11, xch);
}

template<int PC, int PT>
__device__ __forceinline__ void crx_t(float2 (&a)[REGS], int tid, int idx,
                                      const float2* gcs, float4* xch) {
    const float2 g = gcs[idx];
    const float cr = g.x, sr = g.y;
    if constexpr (PT < 4)
        crx_local<(PT < 4 ? PT : 0), PC>(a, tid, cr, sr);
    else if constexpr (PT < 10)
        crx_lane<(PT >= 4 && PT < 10 ? (1 << (PT - 4)) : 1), PC>(a, tid, cr, sr);
    else if constexpr (PC >= 4)
        crx_wave_hi<(PT >= 10 ? (1 << (PT - 4)) : 64), (PC >= 4 ? PC : 4)>(a, tid, cr, sr, xch);
    else
        crx_wave_lo<(PT >= 10 ? (1 << (PT - 4)) : 64), (PC < 4 ? PC : 0)>(a, tid, cr, sr, xch);
}

template<int I>
struct GateSeq {
    __device__ __forceinline__ static void run1q(float2 (&a)[REGS], int tid, int base,
                                                 const float2* gcs, float4* xch) {
        fused1q_t<NQ - 1 - I>(a, tid, base + 3 * I, gcs, xch);
        GateSeq<I + 1>::run1q(a, tid, base, gcs, xch);
    }
    __device__ __forceinline__ static void runAsc(float2 (&a)[REGS], int tid, int base,
                                                  const float2* gcs, float4* xch) {
        crx_t<NQ - 1 - I, NQ - 1 - ((I + 1) % NQ)>(a, tid, base + I, gcs, xch);
        GateSeq<I + 1>::runAsc(a, tid, base, gcs, xch);
    }
    __device__ __forceinline__ static void runDesc(float2 (&a)[REGS], int tid, int base,
                                                   const float2* gcs, float4* xch) {
        constexpr int i = NQ - 1 - I;                       // i = 13..0
        crx_t<NQ - 1 - i, NQ - 1 - ((i + 13) % NQ)>(a, tid, base + I, gcs, xch);
        GateSeq<I + 1>::runDesc(a, tid, base, gcs, xch);
    }
};
template<>
struct GateSeq<NQ> {
    __device__ __forceinline__ static void run1q (float2 (&)[REGS], int, int, const float2*, float4*) {}
    __device__ __forceinline__ static void runAsc(float2 (&)[REGS], int, int, const float2*, float4*) {}
    __device__ __forceinline__ static void runDesc(float2 (&)[REGS], int, int, const float2*, float4*) {}
};

__global__ __launch_bounds__(THREADS, 4)   // 4 waves/EU = exactly 1 block/CU -> 128 VGPR cap
void qsim_kernel(const float* __restrict__ params,
                 unsigned int* __restrict__ out_u32) {
    __shared__ float4 xch[8192];       // 128 KiB exchange, column-major [8][1024]
    __shared__ float2 gcs[NPARAMS];    // (cos, sin) of half-angles

    const int b   = blockIdx.x;
    const int tid = threadIdx.x;

    if (tid < NPARAMS) {
        float s, c;
        sincosf(0.5f * params[b * NPARAMS + tid], &s, &c);
        gcs[tid] = make_float2(c, s);
    }

    float2 a[REGS];
    #pragma unroll
    for (int r = 0; r < REGS; ++r) a[r] = make_float2(0.f, 0.f);
    if (tid == 0) a[0] = make_float2(1.f, 0.f);
    __syncthreads();

    // layer 0
    GateSeq<0>::run1q (a, tid, 0,   gcs, xch);
    GateSeq<0>::runAsc(a, tid, 42,  gcs, xch);
    GateSeq<0>::runDesc(a, tid, 56, gcs, xch);
    // layer 1
    GateSeq<0>::run1q (a, tid, 70,  gcs, xch);
    GateSeq<0>::runAsc(a, tid, 112, gcs, xch);
    GateSeq<0>::runDesc(a, tid, 126, gcs, xch);

    // ---- epilogue: IMAG-FIRST interleaved bf16: low=Im, high=Re ----
    uint4* ob = (uint4*)(out_u32 + (size_t)b * NSTATE + tid * REGS);
    #pragma unroll
    for (int m = 0; m < 4; ++m) {
        uint4 w;
        w.x = f2bf(a[4*m    ].y) | (f2bf(a[4*m    ].x) << 16);
        w.y = f2bf(a[4*m + 1].y) | (f2bf(a[4*m + 1].x) << 16);
        w.z = f2bf(a[4*m + 2].y) | (f2bf(a[4*m + 2].x) << 16);
        w.w = f2bf(a[4*m + 3].y) | (f2bf(a[4*m + 3].x) << 16);
        ob[m] = w;
    }
}

extern "C" void kernel_launch(void* const* d_in, const int* in_sizes, int n_in,
                              void* d_out, int out_size, void* d_ws, size_t ws_size,
                              hipStream_t stream) {
    const float* params = (const float*)d_in[0];
    unsigned int* out = (unsigned int*)d_out;
    qsim_kernel<<<BATCH, THREADS, 0, stream>>>(params, out);
}

// Round 25
// 108.740 us; speedup vs baseline: 1.2681x; 1.0155x over previous
//
#include <hip/hip_runtime.h>
#include <math.h>

constexpr int NQ      = 14;
constexpr int NSTATE  = 1 << 14;    // 16384
constexpr int NPARAMS = 140;
constexpr int BATCH   = 128;
constexpr int THREADS = 1024;
constexpr int REGS    = 16;         // amps per thread: global index i = (tid<<4)|r

struct cplx { float re, im; };
__device__ __forceinline__ cplx cmul(cplx a, cplx b) {
    return { a.re*b.re - a.im*b.im, a.re*b.im + a.im*b.re };
}
__device__ __forceinline__ float2 axpb(cplx A, float2 own, cplx B, float2 par) {
    return make_float2(A.re*own.x - A.im*own.y + B.re*par.x - B.im*par.y,
                       A.re*own.y + A.im*own.x + B.re*par.y + B.im*par.x);
}
__device__ __forceinline__ unsigned int f2bf(float f) {
    union { float f; unsigned int u; } v; v.f = f;
    return (v.u + 0x7FFFu + ((v.u >> 16) & 1u)) >> 16;
}
// insert a set bit at position PCL into 3-bit index j (compile-time use only)
__device__ __forceinline__ constexpr int ins1(int j, int pcl) {
    int lo = j & ((1 << pcl) - 1);
    return ((j ^ lo) << 1) | (1 << pcl) | lo;
}
__device__ __forceinline__ void gate_fence() {
    __builtin_amdgcn_sched_barrier(0);   // stop cross-gate hoisting (live-range cap)
}

// ---------- 1q gate, register bit P (0..3) ----------
template<int P>
__device__ __forceinline__ void u1_local(float2 (&a)[REGS],
                                         cplx u00, cplx u01, cplx u10, cplx u11) {
    #pragma unroll
    for (int r = 0; r < REGS; ++r) {
        if (r & (1 << P)) continue;
        const int r1 = r | (1 << P);
        float2 n0 = axpb(u00, a[r],  u01, a[r1]);
        float2 n1 = axpb(u11, a[r1], u10, a[r]);
        a[r] = n0; a[r1] = n1;
    }
}

// ---------- 1q gate, lane bit (MASK = 1..32) ----------
template<int MASK>
__device__ __forceinline__ void u1_lane(float2 (&a)[REGS], int tid,
                                        cplx u00, cplx u01, cplx u10, cplx u11) {
    const bool hi = (tid & MASK) != 0;
    const cplx A = hi ? u11 : u00;
    const cplx B = hi ? u10 : u01;
    #pragma unroll
    for (int r = 0; r < REGS; ++r) {
        float px = __shfl_xor(a[r].x, MASK, 64);
        float py = __shfl_xor(a[r].y, MASK, 64);
        a[r] = axpb(A, a[r], B, make_float2(px, py));
    }
}

// ---------- 1q gate, wave bit TMASK (64..512 in tid space) ----------
template<int TMASK>
__device__ __forceinline__ void u1_wave(float2 (&a)[REGS], int tid,
                                        cplx u00, cplx u01, cplx u10, cplx u11,
                                        float4* xch) {
    const bool hi = (tid & TMASK) != 0;
    const cplx A = hi ? u11 : u00;
    const cplx B = hi ? u10 : u01;
    __syncthreads();                       // previous xch readers done
    #pragma unroll
    for (int j = 0; j < 8; ++j)            // column-major float4: measured conflict-free
        xch[j*1024 + tid] = make_float4(a[2*j].x, a[2*j].y, a[2*j+1].x, a[2*j+1].y);
    __syncthreads();
    const int pr = tid ^ TMASK;
    #pragma unroll
    for (int j = 0; j < 8; ++j) {
        float4 p = xch[j*1024 + pr];
        a[2*j]   = axpb(A, a[2*j],   B, make_float2(p.x, p.y));
        a[2*j+1] = axpb(A, a[2*j+1], B, make_float2(p.z, p.w));
    }
}

// ---------- CRX, target reg bit PT (0..3), control bit PC ----------
template<int PT, int PC>
__device__ __forceinline__ void crx_local(float2 (&a)[REGS], int tid,
                                          float cr, float sr) {
    #pragma unroll
    for (int r = 0; r < REGS; ++r) {
        if (r & (1 << PT)) continue;
        const int r1 = r | (1 << PT);
        const bool act = ((((tid << 4) | r) >> PC) & 1) != 0;
        if (act) {
            float2 a0 = a[r], a1 = a[r1];
            a[r]  = make_float2(cr*a0.x + sr*a1.y, cr*a0.y - sr*a1.x);
            a[r1] = make_float2(cr*a1.x + sr*a0.y, cr*a1.y - sr*a0.x);
        }
    }
}

// ---------- CRX, target lane bit MASK, control bit PC ----------
template<int MASK, int PC>
__device__ __forceinline__ void crx_lane(float2 (&a)[REGS], int tid,
                                         float cr, float sr) {
    if (PC >= 4) {
        const bool act = ((tid >> (PC - 4)) & 1) != 0;
        #pragma unroll
        for (int r = 0; r < REGS; ++r) {
            float px = __shfl_xor(a[r].x, MASK, 64);
            float py = __shfl_xor(a[r].y, MASK, 64);
            if (act) a[r] = make_float2(cr*a[r].x + sr*py, cr*a[r].y - sr*px);
        }
    } else {
        #pragma unroll
        for (int r = 0; r < REGS; ++r) {
            if (((r >> PC) & 1) == 0) continue;      // inactive reg: skip shuffle
            float px = __shfl_xor(a[r].x, MASK, 64);
            float py = __shfl_xor(a[r].y, MASK, 64);
            a[r] = make_float2(cr*a[r].x + sr*py, cr*a[r].y - sr*px);
        }
    }
}

// ---------- CRX, target wave bit TMASK, control bit PC >= 4 ----------
template<int TMASK, int PC>
__device__ __forceinline__ void crx_wave_hi(float2 (&a)[REGS], int tid,
                                            float cr, float sr, float4* xch) {
    const bool act = (tid & (1 << (PC - 4))) != 0;
    __syncthreads();
    if (act) {
        #pragma unroll
        for (int j = 0; j < 8; ++j)
            xch[j*1024 + tid] = make_float4(a[2*j].x, a[2*j].y, a[2*j+1].x, a[2*j+1].y);
    }
    __syncthreads();
    if (act) {
        const int pr = tid ^ TMASK;
        #pragma unroll
        for (int j = 0; j < 8; ++j) {
            float4 p = xch[j*1024 + pr];
            a[2*j]   = make_float2(cr*a[2*j].x   + sr*p.y, cr*a[2*j].y   - sr*p.x);
            a[2*j+1] = make_float2(cr*a[2*j+1].x + sr*p.w, cr*a[2*j+1].y - sr*p.z);
        }
    }
}

// ---------- CRX, target wave bit TMASK, control reg bit PCL (0..3) ----------
template<int TMASK, int PCL>
__device__ __forceinline__ void crx_wave_lo(float2 (&a)[REGS], int tid,
                                            float cr, float sr, float4* xch) {
    __syncthreads();
    #pragma unroll
    for (int j2 = 0; j2 < 4; ++j2) {
        constexpr int ra0[4] = { ins1(0,PCL), ins1(2,PCL), ins1(4,PCL), ins1(6,PCL) };
        constexpr int rb0[4] = { ins1(1,PCL), ins1(3,PCL), ins1(5,PCL), ins1(7,PCL) };
        xch[j2*1024 + tid] = make_float4(a[ra0[j2]].x, a[ra0[j2]].y,
                                         a[rb0[j2]].x, a[rb0[j2]].y);
    }
    __syncthreads();
    const int pr = tid ^ TMASK;
    #pragma unroll
    for (int j2 = 0; j2 < 4; ++j2) {
        constexpr int ra0[4] = { ins1(0,PCL), ins1(2,PCL), ins1(4,PCL), ins1(6,PCL) };
        constexpr int rb0[4] = { ins1(1,PCL), ins1(3,PCL), ins1(5,PCL), ins1(7,PCL) };
        float4 p = xch[j2*1024 + pr];
        const int ra = ra0[j2], rb = rb0[j2];
        a[ra] = make_float2(cr*a[ra].x + sr*p.y, cr*a[ra].y - sr*p.x);
        a[rb] = make_float2(cr*a[rb].x + sr*p.w, cr*a[rb].y - sr*p.z);
    }
}

// ---------- compile-time dispatchers ----------
template<int P>
__device__ __forceinline__ void fused1q_t(float2 (&a)[REGS], int tid, int idx,
                                          const float2* gcs, float4* xch) {
    const float2 x = gcs[idx], y = gcs[idx + 1], z = gcs[idx + 2];
    const float cx = x.x, sx = x.y, cy = y.x, sy = y.y, cz = z.x, sz = z.y;
    cplx m00{ cy*cx,  sy*sx }, m01{ -sy*cx, -cy*sx };
    cplx m10{ sy*cx, -cy*sx }, m11{  cy*cx, -sy*sx };
    cplx z0{ cz, -sz }, z1{ cz, sz };
    cplx u00 = cmul(z0, m00), u01 = cmul(z0, m01);
    cplx u10 = cmul(z1, m10), u11 = cmul(z1, m11);
    if constexpr (P < 4)       u1_local<(P < 4 ? P : 0)>(a, u00, u01, u10, u11);
    else if constexpr (P < 10) u1_lane<(P >= 4 && P < 10 ? (1 << (P - 4)) : 1)>(a, tid, u00, u01, u10, u11);
    else                       u1_wave<(P >= 10 ? (1 << (P - 4)) : 64)>(a, tid, u00, u01, u10, u11, xch);
}

template<int PC, int PT>
__device__ __forceinline__ void crx_t(float2 (&a)[REGS], int tid, int idx,
                                      const float2* gcs, float4* xch) {
    const float2 g = gcs[idx];
    const float cr = g.x, sr = g.y;
    if constexpr (PT < 4)
        crx_local<(PT < 4 ? PT : 0), PC>(a, tid, cr, sr);
    else if constexpr (PT < 10)
        crx_lane<(PT >= 4 && PT < 10 ? (1 << (PT - 4)) : 1), PC>(a, tid, cr, sr);
    else if constexpr (PC >= 4)
        crx_wave_hi<(PT >= 10 ? (1 << (PT - 4)) : 64), (PC >= 4 ? PC : 4)>(a, tid, cr, sr, xch);
    else
        crx_wave_lo<(PT >= 10 ? (1 << (PT - 4)) : 64), (PC < 4 ? PC : 0)>(a, tid, cr, sr, xch);
}

template<int I>
struct GateSeq {
    __device__ __forceinline__ static void run1q(float2 (&a)[REGS], int tid, int base,
                                                 const float2* gcs, float4* xch) {
        fused1q_t<NQ - 1 - I>(a, tid, base + 3 * I, gcs, xch);
        gate_fence();
        GateSeq<I + 1>::run1q(a, tid, base, gcs, xch);
    }
    __device__ __forceinline__ static void runAsc(float2 (&a)[REGS], int tid, int base,
                                                  const float2* gcs, float4* xch) {
        crx_t<NQ - 1 - I, NQ - 1 - ((I + 1) % NQ)>(a, tid, base + I, gcs, xch);
        gate_fence();
        GateSeq<I + 1>::runAsc(a, tid, base, gcs, xch);
    }
    __device__ __forceinline__ static void runDesc(float2 (&a)[REGS], int tid, int base,
                                                   const float2* gcs, float4* xch) {
        constexpr int i = NQ - 1 - I;                       // i = 13..0
        crx_t<NQ - 1 - i, NQ - 1 - ((i + 13) % NQ)>(a, tid, base + I, gcs, xch);
        gate_fence();
        GateSeq<I + 1>::runDesc(a, tid, base, gcs, xch);
    }
};
template<>
struct GateSeq<NQ> {
    __device__ __forceinline__ static void run1q (float2 (&)[REGS], int, int, const float2*, float4*) {}
    __device__ __forceinline__ static void runAsc(float2 (&)[REGS], int, int, const float2*, float4*) {}
    __device__ __forceinline__ static void runDesc(float2 (&)[REGS], int, int, const float2*, float4*) {}
};

// Exactly 4 waves/EU (1 block/CU, forced by 128 KiB LDS anyway) -> 128-VGPR budget.
__global__
__attribute__((amdgpu_flat_work_group_size(1024, 1024)))
__attribute__((amdgpu_waves_per_eu(4, 4)))
void qsim_kernel(const float* __restrict__ params,
                 unsigned int* __restrict__ out_u32) {
    __shared__ float4 xch[8192];       // 128 KiB exchange, column-major [8][1024]
    __shared__ float2 gcs[NPARAMS];    // (cos, sin) of half-angles

    const int b   = blockIdx.x;
    const int tid = threadIdx.x;

    if (tid < NPARAMS) {
        float s, c;
        sincosf(0.5f * params[b * NPARAMS + tid], &s, &c);
        gcs[tid] = make_float2(c, s);
    }

    float2 a[REGS];
    #pragma unroll
    for (int r = 0; r < REGS; ++r) a[r] = make_float2(0.f, 0.f);
    if (tid == 0) a[0] = make_float2(1.f, 0.f);
    __syncthreads();

    // layer 0
    GateSeq<0>::run1q (a, tid, 0,   gcs, xch);
    GateSeq<0>::runAsc(a, tid, 42,  gcs, xch);
    GateSeq<0>::runDesc(a, tid, 56, gcs, xch);
    // layer 1
    GateSeq<0>::run1q (a, tid, 70,  gcs, xch);
    GateSeq<0>::runAsc(a, tid, 112, gcs, xch);
    GateSeq<0>::runDesc(a, tid, 126, gcs, xch);

    // ---- epilogue: IMAG-FIRST interleaved bf16: low=Im, high=Re ----
    uint4* ob = (uint4*)(out_u32 + (size_t)b * NSTATE + tid * REGS);
    #pragma unroll
    for (int m = 0; m < 4; ++m) {
        uint4 w;
        w.x = f2bf(a[4*m    ].y) | (f2bf(a[4*m    ].x) << 16);
        w.y = f2bf(a[4*m + 1].y) | (f2bf(a[4*m + 1].x) << 16);
        w.z = f2bf(a[4*m + 2].y) | (f2bf(a[4*m + 2].x) << 16);
        w.w = f2bf(a[4*m + 3].y) | (f2bf(a[4*m + 3].x) << 16);
        ob[m] = w;
    }
}

extern "C" void kernel_launch(void* const* d_in, const int* in_sizes, int n_in,
                              void* d_out, int out_size, void* d_ws, size_t ws_size,
                              hipStream_t stream) {
    const float* params = (const float*)d_in[0];
    unsigned int* out = (unsigned int*)d_out;
    qsim_kernel<<<BATCH, THREADS, 0, stream>>>(params, out);
}